// Round 8
// baseline (721.248 us; speedup 1.0000x reference)
//
#include <hip/hip_runtime.h>
#include <hip/hip_fp16.h>
#include <math.h>

// Reference: bev (1024,1,120,120) fp32 -> out (1024,120) fp32.
// R15 green @600us: VALUBusy 76%, occupancy 44.8% (1 blk/CU, LDS-capped),
// conflicts 1.344e8 cyc = 37% of dispatch cycles; LDS pipe ~67% busy.
// Bank analysis: per-lane stride = ct + 123*st texels; 8B texels -> word
// stride 2*dAi mod 32. Angles with dAi ~ 0 mod 16 put 64 lanes in ~2 banks
// (16x reads); those waves then idle at the chunk barrier.
// R16: QUADRATIC ROW-SHEAR of H: texel (y,x) stored at y*131 + x + d(y),
// d(y) = (y*(y+1)/2) & 7. Constant within a row => ds_read2_b64 x-pairing
// intact; row-to-row stride = 131 + ((y+1) mod 8) varies => bank patterns
// decorrelate exactly for the degenerate angles (small-st angles are safe:
// |dAi| <= 14 < 16). Linear shears DON'T work (constant stride mod 32).
// Cost: ~+10 VALU/sample shared by 4 images; H = 123*131*8 = 128.9 KB ->
// drop schunk double-buffer (R14's 2-barrier/chunk structure), 145.3 KB.
// Accumulation path untouched -> output bit-identical (canary 4.882812e-4).
#define NPIX  120
#define NS    120
#define NK    61             // independent bins 0..60; 61..119 mirrored
#define HROWS 123            // y = 0..122 (pads at 0, 121, 122)
#define HSTR2 131            // sheared row stride: 123 cols + max shear 7 + 1
#define CHUNK 8              // angles in flight
#define NCHUNK 15            // 120 / 8
#define NT    960            // 8 angle-slots x 120, 15 waves

#if __has_builtin(__builtin_amdgcn_fractf)
#define FRACTF(x) __builtin_amdgcn_fractf(x)
#else
#define FRACTF(x) ((x) - floorf(x))
#endif

__device__ __forceinline__ int shearD(int y) {      // (y*(y+1)/2) & 7
    return (__mul24(y, y + 1) >> 1) & 7;
}
__device__ __forceinline__ __half2 lo_h2(uint2 q) { return *reinterpret_cast<__half2*>(&q.x); }
__device__ __forceinline__ __half2 hi_h2(uint2 q) { return *reinterpret_cast<__half2*>(&q.y); }

// LDS: H 123*131*8 (128,904) + schunk 8*120*16 (15,360) + outAcc 976 + 16
//    = 145,256 B -> 1 block/CU, 15 waves.

__global__ void ring_fused(const float* __restrict__ bev,
                           float* __restrict__ out,
                           int B) {
    __shared__ uint2  H[HROWS * HSTR2];   // (A,B,C,D) 4xfp16, row-sheared
    __shared__ float4 schunk[CHUNK * NS]; // 8 sinogram rows x 4 images
    __shared__ float4 outAcc[NK];
    __shared__ float  invN[4];            // per-image 1/norm (scalar stores)

    const int tid = threadIdx.x;          // 0..959
    const int b0  = blockIdx.x * 4;       // first image of the quad
    const int al  = tid / NS;             // angle slot 0..7
    const int sk  = tid - al * NS;        // s (radon) / k (Goertzel, if <61)
    if (b0 >= B) return;

    // ---- stage: build sheared H from 4 images (1 thread per logical texel) --
    const float* s0 = bev + (size_t)b0 * (NPIX * NPIX);
    const float* s1 = (b0 + 1 < B) ? bev + (size_t)(b0 + 1) * (NPIX * NPIX) : s0;
    const float* s2 = (b0 + 2 < B) ? bev + (size_t)(b0 + 2) * (NPIX * NPIX) : s0;
    const float* s3 = (b0 + 3 < B) ? bev + (size_t)(b0 + 3) * (NPIX * NPIX) : s0;
    for (int i = tid; i < HROWS * 123; i += NT) {
        int y = i / 123, x = i - y * 123;
        float va = 0.f, vb = 0.f, vc = 0.f, vd = 0.f;
        int gx = x - 1, gy = y - 1;
        if (gx >= 0 && gx < NPIX && gy >= 0 && gy < NPIX) {
            int o = gy * NPIX + gx;
            va = s0[o]; vb = s1[o]; vc = s2[o]; vd = s3[o];
        }
        __half2 ab = __floats2half2_rn(va, vb);
        __half2 cd = __floats2half2_rn(vc, vd);
        H[__mul24(y, HSTR2) + x + shearD(y)] =
            make_uint2(*reinterpret_cast<unsigned*>(&ab),
                       *reinterpret_cast<unsigned*>(&cd));
    }
    __syncthreads();

    // ---- per-thread Goertzel constant (k = sk, used where sk < 61) ---------
    const float coef = 2.f * cosf((float)sk * 0.052359877559829887f);  // 2cos(pi k/60)
    const float sgn  = (sk & 1) ? -1.f : 1.f;
    const double STEP = 6.283185307179586 / 119.0;   // linspace(0,2pi,120) step
    float acc0 = 0.f, acc1 = 0.f, acc2 = 0.f, acc3 = 0.f;

    for (int ch = 0; ch < NCHUNK; ++ch) {
        // ---- radon: sinogram[a = ch*8+al][s = sk] for FOUR images ----------
        {
            int a = ch * CHUNK + al;
            float theta = (float)((double)a * STEP);
            float st = sinf(theta), ct = cosf(theta);
            float sf  = (float)sk - 59.5f;
            float Ax  = fmaf(sf, ct, 60.5f);   // padded px at tv=0
            float Ay  = fmaf(sf, st, 60.5f);   // padded py at tv=0
            float nst = -st;
            float aA0 = 0.f, aA1 = 0.f, aB0 = 0.f, aB1 = 0.f;  // parity chains
            float aC0 = 0.f, aC1 = 0.f, aD0 = 0.f, aD1 = 0.f;
            float tv  = -59.5f;
            #pragma unroll 4
            for (int t = 0; t < NPIX; ++t) {
                float px = fmaf(tv, nst, Ax);
                float py = fmaf(tv, ct,  Ay);
                float cx = fminf(fmaxf(px, 0.f), 121.5f);  // v_med3
                float cy = fminf(fmaxf(py, 0.f), 121.5f);
                int   ix = (int)cx;                        // trunc = floor (cx>=0)
                int   iy = (int)cy;
                float wx = FRACTF(cx);                     // == cx - floor(cx)
                float wy = FRACTF(cy);
                int   iy1 = iy + 1;
                int   d1  = (__mul24(iy,  iy1)    >> 1) & 7;
                int   d2  = (__mul24(iy1, iy + 2) >> 1) & 7;
                int   ai  = __mul24(iy,  HSTR2) + ix + d1;
                int   ai2 = __mul24(iy1, HSTR2) + ix + d2;
                uint2 q00 = H[ai];                         // ds_read2_b64 0/1
                uint2 q01 = H[ai + 1];
                uint2 q10 = H[ai2];                        // ds_read2_b64 0/1
                uint2 q11 = H[ai2 + 1];
                __half2 wx2 = __float2half2_rn(wx);
                __half2 wy2 = __float2half2_rn(wy);
                __half2 abT = __hfma2(wx2, __hsub2(lo_h2(q01), lo_h2(q00)), lo_h2(q00));
                __half2 abB = __hfma2(wx2, __hsub2(lo_h2(q11), lo_h2(q10)), lo_h2(q10));
                __half2 abV = __hfma2(wy2, __hsub2(abB, abT), abT);
                __half2 cdT = __hfma2(wx2, __hsub2(hi_h2(q01), hi_h2(q00)), hi_h2(q00));
                __half2 cdB = __hfma2(wx2, __hsub2(hi_h2(q11), hi_h2(q10)), hi_h2(q10));
                __half2 cdV = __hfma2(wy2, __hsub2(cdB, cdT), cdT);
                if (t & 1) {
                    aA1 += __low2float(abV); aB1 += __high2float(abV);
                    aC1 += __low2float(cdV); aD1 += __high2float(cdV);
                } else {
                    aA0 += __low2float(abV); aB0 += __high2float(abV);
                    aC0 += __low2float(cdV); aD0 += __high2float(cdV);
                }
                tv += 1.f;
            }
            schunk[al * NS + sk] = make_float4(aA0 + aA1, aB0 + aB1,
                                               aC0 + aC1, aD0 + aD1);
        }
        __syncthreads();

        // ---- Goertzel: |F[k = sk]| of row al, 4 images (sk < 61) -----------
        if (sk < NK) {
            const float4* row = schunk + al * NS;
            float u1a = 0.f, u2a = 0.f, u1b = 0.f, u2b = 0.f;
            float u1c = 0.f, u2c = 0.f, u1d = 0.f, u2d = 0.f;
            #pragma unroll 4
            for (int s = 0; s < 60; ++s) {
                float4 lo = row[s];            // broadcast ds_read_b128
                float4 hi = row[s + 60];
                float wa = fmaf(sgn, hi.x, lo.x);
                float wb = fmaf(sgn, hi.y, lo.y);
                float wc = fmaf(sgn, hi.z, lo.z);
                float wd = fmaf(sgn, hi.w, lo.w);
                float va = fmaf(coef, u1a, wa - u2a); u2a = u1a; u1a = va;
                float vb = fmaf(coef, u1b, wb - u2b); u2b = u1b; u1b = vb;
                float vc = fmaf(coef, u1c, wc - u2c); u2c = u1c; u1c = vc;
                float vd = fmaf(coef, u1d, wd - u2d); u2d = u1d; u1d = vd;
            }
            float pa = fmaf(u1a, u1a, fmaf(u2a, u2a, -coef * u1a * u2a));
            float pb = fmaf(u1b, u1b, fmaf(u2b, u2b, -coef * u1b * u2b));
            float pc = fmaf(u1c, u1c, fmaf(u2c, u2c, -coef * u1c * u2c));
            float pd = fmaf(u1d, u1d, fmaf(u2d, u2d, -coef * u1d * u2d));
            pa = fmaxf(pa, 0.f); pb = fmaxf(pb, 0.f);
            pc = fmaxf(pc, 0.f); pd = fmaxf(pd, 0.f);
            acc0 += sqrtf(fmaf(pa, (1.f / 120.f), 1e-15f));  // ortho + EPS_FFT
            acc1 += sqrtf(fmaf(pb, (1.f / 120.f), 1e-15f));
            acc2 += sqrtf(fmaf(pc, (1.f / 120.f), 1e-15f));
            acc3 += sqrtf(fmaf(pd, (1.f / 120.f), 1e-15f));
        }
        __syncthreads();   // Goertzel reads done before next chunk overwrites
    }

    // ---- reduce 8 angle-slot partials per bin (deterministic) --------------
    if (sk < NK) schunk[al * NS + sk] = make_float4(acc0, acc1, acc2, acc3);
    __syncthreads();
    if (tid < NK) {
        float sa = 0.f, sb = 0.f, sc = 0.f, sd = 0.f;
        for (int a2 = 0; a2 < CHUNK; ++a2) {
            float4 v = schunk[a2 * NS + tid];
            sa += v.x; sb += v.y; sc += v.z; sd += v.w;
        }
        outAcc[tid] = make_float4(sa, sb, sc, sd);
    }
    __syncthreads();

    // ---- L2 norm over the full mirrored 120-vector, one thread per image ---
    if (tid < 4) {
        float ssq = 0.f;
        for (int k = 0; k < NK; ++k) {
            float v = ((const float*)&outAcc[k])[tid];
            float wgt = (k == 0 || k == 60) ? 1.f : 2.f;
            ssq = fmaf(wgt * v, v, ssq);
        }
        invN[tid] = 1.f / fmaxf(sqrtf(ssq), 1e-12f);  // per-lane scalar store
    }
    __syncthreads();

    // ---- write fp32 output (Hermitian mirror), 4 images --------------------
    if (tid < 4 * NPIX) {
        int img = tid / NPIX;
        int j   = tid - img * NPIX;
        int k   = (j <= 60) ? j : (NPIX - j);
        int bb  = b0 + img;
        if (bb < B) {
            float v = ((const float*)&outAcc[k])[img] * invN[img];
            out[(size_t)bb * NPIX + j] = v;
        }
    }
}

extern "C" void kernel_launch(void* const* d_in, const int* in_sizes, int n_in,
                              void* d_out, int out_size, void* d_ws, size_t ws_size,
                              hipStream_t stream) {
    const float* bev = (const float*)d_in[0];
    float* out = (float*)d_out;
    int B = in_sizes[0] / (NPIX * NPIX);   // 1024
    int grid = (B + 3) / 4;                // 4 images per block
    hipLaunchKernelGGL(ring_fused, dim3(grid), dim3(NT), 0, stream, bev, out, B);
}

// Round 10
// 642.209 us; speedup vs baseline: 1.1231x; 1.1231x over previous
//
#include <hip/hip_runtime.h>
#include <hip/hip_fp16.h>
#include <math.h>

// Reference: bev (1024,1,120,120) fp32 -> out (1024,120) fp32.
// R15 green @600us: VALUBusy 76%, occupancy 44.8% (1 blk/CU), conflicts
// 1.344e8 cyc (37% of dispatch); LDS pipe ~67% busy. 4 images/block packed
// as 4xfp16 in uint2 texels H[y][x]=(A,B,C,D), stride 123.
// R16 (row-shear) REFUTED: conflicts UP to 1.78e8, 721us. Shear is locally
// constant within 16-lane phase groups (iy changes only every ~1/st lanes)
// and the new stride moved the degenerate-angle set. Fully reverted.
// R17 (re-run; two prior submissions died to container-acquire infra flakes,
// same signature as Rounds 2/6 which re-ran fine) = R15 + RADON LANE REMAP:
// al = tid&7, sk = tid>>3. A wave's 64 lanes now span 8 ANGLES x 8 s-values,
// so any 16-lane phase group holds <=2 lanes per angle (2-way max from the
// old per-angle stride pathology; the 8 angle bases spread along a ~21-degree
// arc -> distinct banks except the small-radius core). One degenerate angle
// can no longer collide a whole wave.
// BIT-IDENTICAL: each (a,s) ray computed by exactly one thread, same t-order,
// same schunk slot -- only thread roles permute. Zero extra inner-loop VALU.
// Goertzel/reduce phases keep their own mapping (barrier-separated).
// Canary: absmax exactly 4.882812e-4.
#define NPIX  120
#define NS    120
#define NK    61             // independent bins 0..60; 61..119 mirrored
#define HSTR  123            // H cols: x = 0..122 (pads at 0, 121, 122)
#define HROWS 123            // H rows: y = 0..122 (pads at 0, 121, 122)
#define CHUNK 8              // angles in flight
#define NCHUNK 15            // 120 / 8
#define NT    960            // 15 waves

#if __has_builtin(__builtin_amdgcn_fractf)
#define FRACTF(x) __builtin_amdgcn_fractf(x)
#else
#define FRACTF(x) ((x) - floorf(x))
#endif

__device__ __forceinline__ __half2 lo_h2(uint2 q) { return *reinterpret_cast<__half2*>(&q.x); }
__device__ __forceinline__ __half2 hi_h2(uint2 q) { return *reinterpret_cast<__half2*>(&q.y); }

// LDS: H 123*123*8 (121,032) + schunk dbl 2*8*120*16 (30,720) + outAcc 976
//    + invN 16 = 152,744 B -> 1 block/CU, 15 waves.

__global__ void ring_fused(const float* __restrict__ bev,
                           float* __restrict__ out,
                           int B) {
    __shared__ uint2  H[HROWS * HSTR];       // (A,B,C,D) 4xfp16 padded image
    __shared__ float4 schunk[2][CHUNK * NS]; // double-buffered sinogram rows
    __shared__ float4 outAcc[NK];
    __shared__ float  invN[4];               // per-image 1/norm (scalar stores)

    const int tid = threadIdx.x;          // 0..959
    const int b0  = blockIdx.x * 4;       // first image of the quad
    const int al  = tid / NS;             // Goertzel-phase angle slot 0..7
    const int sk  = tid - al * NS;        // Goertzel-phase k (if <61)
    const int alr = tid & 7;              // RADON-phase angle slot 0..7
    const int skr = tid >> 3;             // RADON-phase s index 0..119
    if (b0 >= B) return;

    // ---- stage: build H from 4 images (each 8B word owned by 1 thread) -----
    const float* s0 = bev + (size_t)b0 * (NPIX * NPIX);
    const float* s1 = (b0 + 1 < B) ? bev + (size_t)(b0 + 1) * (NPIX * NPIX) : s0;
    const float* s2 = (b0 + 2 < B) ? bev + (size_t)(b0 + 2) * (NPIX * NPIX) : s0;
    const float* s3 = (b0 + 3 < B) ? bev + (size_t)(b0 + 3) * (NPIX * NPIX) : s0;
    for (int i = tid; i < HROWS * HSTR; i += NT) {
        int y = i / HSTR, x = i - y * HSTR;
        float va = 0.f, vb = 0.f, vc = 0.f, vd = 0.f;
        int gx = x - 1, gy = y - 1;
        if (gx >= 0 && gx < NPIX && gy >= 0 && gy < NPIX) {
            int o = gy * NPIX + gx;
            va = s0[o]; vb = s1[o]; vc = s2[o]; vd = s3[o];
        }
        __half2 ab = __floats2half2_rn(va, vb);
        __half2 cd = __floats2half2_rn(vc, vd);
        H[i] = make_uint2(*reinterpret_cast<unsigned*>(&ab),
                          *reinterpret_cast<unsigned*>(&cd));
    }
    __syncthreads();

    // ---- per-thread Goertzel constant (k = sk, used where sk < 61) ---------
    const float coef = 2.f * cosf((float)sk * 0.052359877559829887f);  // 2cos(pi k/60)
    const float sgn  = (sk & 1) ? -1.f : 1.f;
    const double STEP = 6.283185307179586 / 119.0;   // linspace(0,2pi,120) step
    float acc0 = 0.f, acc1 = 0.f, acc2 = 0.f, acc3 = 0.f;

    for (int ch = 0; ch < NCHUNK; ++ch) {
        float4* buf = schunk[ch & 1];
        // ---- radon: sinogram[a = ch*8+alr][s = skr] for FOUR images --------
        {
            int a = ch * CHUNK + alr;
            float theta = (float)((double)a * STEP);
            float st = sinf(theta), ct = cosf(theta);
            float sf  = (float)skr - 59.5f;
            float Ax  = fmaf(sf, ct, 60.5f);   // padded px at tv=0
            float Ay  = fmaf(sf, st, 60.5f);   // padded py at tv=0
            float nst = -st;
            float aA0 = 0.f, aA1 = 0.f, aB0 = 0.f, aB1 = 0.f;  // parity chains
            float aC0 = 0.f, aC1 = 0.f, aD0 = 0.f, aD1 = 0.f;
            float tv  = -59.5f;
            #pragma unroll 4
            for (int t = 0; t < NPIX; ++t) {
                float px = fmaf(tv, nst, Ax);
                float py = fmaf(tv, ct,  Ay);
                float cx = fminf(fmaxf(px, 0.f), 121.5f);  // v_med3
                float cy = fminf(fmaxf(py, 0.f), 121.5f);
                int   ix = (int)cx;                        // trunc = floor (cx>=0)
                int   iy = (int)cy;
                float wx = FRACTF(cx);                     // == cx - floor(cx)
                float wy = FRACTF(cy);
                int   ai = __mul24(iy, HSTR) + ix;
                uint2 q00 = H[ai];                         // ds_read2_b64 0/1
                uint2 q01 = H[ai + 1];
                uint2 q10 = H[ai + HSTR];                  // ds_read2_b64 123/124
                uint2 q11 = H[ai + HSTR + 1];
                __half2 wx2 = __float2half2_rn(wx);
                __half2 wy2 = __float2half2_rn(wy);
                __half2 abT = __hfma2(wx2, __hsub2(lo_h2(q01), lo_h2(q00)), lo_h2(q00));
                __half2 abB = __hfma2(wx2, __hsub2(lo_h2(q11), lo_h2(q10)), lo_h2(q10));
                __half2 abV = __hfma2(wy2, __hsub2(abB, abT), abT);
                __half2 cdT = __hfma2(wx2, __hsub2(hi_h2(q01), hi_h2(q00)), hi_h2(q00));
                __half2 cdB = __hfma2(wx2, __hsub2(hi_h2(q11), hi_h2(q10)), hi_h2(q10));
                __half2 cdV = __hfma2(wy2, __hsub2(cdB, cdT), cdT);
                if (t & 1) {
                    aA1 += __low2float(abV); aB1 += __high2float(abV);
                    aC1 += __low2float(cdV); aD1 += __high2float(cdV);
                } else {
                    aA0 += __low2float(abV); aB0 += __high2float(abV);
                    aC0 += __low2float(cdV); aD0 += __high2float(cdV);
                }
                tv += 1.f;
            }
            buf[alr * NS + skr] = make_float4(aA0 + aA1, aB0 + aB1,
                                              aC0 + aC1, aD0 + aD1);
        }
        __syncthreads();

        // ---- Goertzel: |F[k = sk]| of row al, 4 images (sk < 61) -----------
        // (no trailing barrier: next chunk writes the OTHER schunk buffer;
        //  reuse of THIS buffer in chunk ch+2 is fenced by ch+1's barrier)
        if (sk < NK) {
            const float4* row = buf + al * NS;
            float u1a = 0.f, u2a = 0.f, u1b = 0.f, u2b = 0.f;
            float u1c = 0.f, u2c = 0.f, u1d = 0.f, u2d = 0.f;
            #pragma unroll 4
            for (int s = 0; s < 60; ++s) {
                float4 lo = row[s];            // broadcast ds_read_b128
                float4 hi = row[s + 60];
                float wa = fmaf(sgn, hi.x, lo.x);
                float wb = fmaf(sgn, hi.y, lo.y);
                float wc = fmaf(sgn, hi.z, lo.z);
                float wd = fmaf(sgn, hi.w, lo.w);
                float va = fmaf(coef, u1a, wa - u2a); u2a = u1a; u1a = va;
                float vb = fmaf(coef, u1b, wb - u2b); u2b = u1b; u1b = vb;
                float vc = fmaf(coef, u1c, wc - u2c); u2c = u1c; u1c = vc;
                float vd = fmaf(coef, u1d, wd - u2d); u2d = u1d; u1d = vd;
            }
            float pa = fmaf(u1a, u1a, fmaf(u2a, u2a, -coef * u1a * u2a));
            float pb = fmaf(u1b, u1b, fmaf(u2b, u2b, -coef * u1b * u2b));
            float pc = fmaf(u1c, u1c, fmaf(u2c, u2c, -coef * u1c * u2c));
            float pd = fmaf(u1d, u1d, fmaf(u2d, u2d, -coef * u1d * u2d));
            pa = fmaxf(pa, 0.f); pb = fmaxf(pb, 0.f);
            pc = fmaxf(pc, 0.f); pd = fmaxf(pd, 0.f);
            acc0 += sqrtf(fmaf(pa, (1.f / 120.f), 1e-15f));  // ortho + EPS_FFT
            acc1 += sqrtf(fmaf(pb, (1.f / 120.f), 1e-15f));
            acc2 += sqrtf(fmaf(pc, (1.f / 120.f), 1e-15f));
            acc3 += sqrtf(fmaf(pd, (1.f / 120.f), 1e-15f));
        }
    }
    __syncthreads();   // all Goertzel reads done before schunk[0] is reused

    // ---- reduce 8 angle-slot partials per bin (deterministic) --------------
    if (sk < NK) schunk[0][al * NS + sk] = make_float4(acc0, acc1, acc2, acc3);
    __syncthreads();
    if (tid < NK) {
        float sa = 0.f, sb = 0.f, sc = 0.f, sd = 0.f;
        for (int a2 = 0; a2 < CHUNK; ++a2) {
            float4 v = schunk[0][a2 * NS + tid];
            sa += v.x; sb += v.y; sc += v.z; sd += v.w;
        }
        outAcc[tid] = make_float4(sa, sb, sc, sd);
    }
    __syncthreads();

    // ---- L2 norm over the full mirrored 120-vector, one thread per image ---
    if (tid < 4) {
        float ssq = 0.f;
        for (int k = 0; k < NK; ++k) {
            float v = ((const float*)&outAcc[k])[tid];
            float wgt = (k == 0 || k == 60) ? 1.f : 2.f;
            ssq = fmaf(wgt * v, v, ssq);
        }
        invN[tid] = 1.f / fmaxf(sqrtf(ssq), 1e-12f);  // per-lane scalar store
    }
    __syncthreads();

    // ---- write fp32 output (Hermitian mirror), 4 images --------------------
    if (tid < 4 * NPIX) {
        int img = tid / NPIX;
        int j   = tid - img * NPIX;
        int k   = (j <= 60) ? j : (NPIX - j);
        int bb  = b0 + img;
        if (bb < B) {
            float v = ((const float*)&outAcc[k])[img] * invN[img];
            out[(size_t)bb * NPIX + j] = v;
        }
    }
}

extern "C" void kernel_launch(void* const* d_in, const int* in_sizes, int n_in,
                              void* d_out, int out_size, void* d_ws, size_t ws_size,
                              hipStream_t stream) {
    const float* bev = (const float*)d_in[0];
    float* out = (float*)d_out;
    int B = in_sizes[0] / (NPIX * NPIX);   // 1024
    int grid = (B + 3) / 4;                // 4 images per block
    hipLaunchKernelGGL(ring_fused, dim3(grid), dim3(NT), 0, stream, bev, out, B);
}